// Round 27
// baseline (61.645 us; speedup 1.0000x reference)
//
#include <hip/hip_runtime.h>

#define WCH 256         // targets per wave-private chunk
#define WTPC 8          // MFMA tiles per wave chunk (WCH/32)
#define QPB 512         // queries per block (4 waves x 4 sets x 32 cols)
#define YSL 8           // target slices (grid.y)
#define RB 64           // reduction blocks

typedef __bf16 bf16x8 __attribute__((ext_vector_type(8)));
typedef float f32x16 __attribute__((ext_vector_type(16)));

__device__ __forceinline__ unsigned bfb(float x) {
    __bf16 h = (__bf16)x;
    return (unsigned)__builtin_bit_cast(unsigned short, h);
}
__device__ __forceinline__ float bff(unsigned b) {
    return (float)__builtin_bit_cast(__bf16, (unsigned short)b);
}

// Build the A-fragment pair for one target point (LDS layout within a tile:
// [tile][lane] where lane<32 = k-half 0 (h0), lane>=32 = k-half 1 (h1)).
// score = (d2 - |q|^2)/4 + 320, window [304,384) in binade [256,512).
// Sentinel (invalid): coords 0, u=130 -> score 450 (in-window, never wins).
__device__ __forceinline__ void make_frag(float4 p, bool valid, uint4& h0, uint4& h1) {
    float x, y, z, u;
    if (valid) {
        x = p.x; y = p.y; z = p.z;
        u = 0.25f * fmaf(p.x, p.x, fmaf(p.y, p.y, p.z * p.z));
    } else {
        x = 0.f; y = 0.f; z = 0.f; u = 130.f;
    }
    unsigned xh = bfb(x); unsigned xl = bfb(x - bff(xh));
    unsigned yh = bfb(y); unsigned yl = bfb(y - bff(yh));
    unsigned zh = bfb(z); unsigned zl = bfb(z - bff(zh));
    unsigned uh = bfb(u); float u1 = u - bff(uh);
    unsigned ul = bfb(u1); unsigned ull = bfb(u1 - bff(ul));
    h0.x = xh | (xl << 16); h0.y = h0.x;
    h0.z = yh | (yl << 16); h0.w = h0.z;
    h1.x = zh | (zl << 16); h1.y = h1.x;
    h1.z = uh | (ul << 16);
    h1.w = ull | (0x43A0u << 16);      // [ull, bf16(320)]
}

// build B fragment for one query point (c = -q/2 split hi/lo)
__device__ __forceinline__ bf16x8 make_bfrag(float4 qp, int h) {
    float cx = -0.5f * qp.x, cy = -0.5f * qp.y, cz = -0.5f * qp.z;
    unsigned cxh = bfb(cx); unsigned cxl = bfb(cx - bff(cxh));
    unsigned cyh = bfb(cy); unsigned cyl = bfb(cy - bff(cyh));
    unsigned czh = bfb(cz); unsigned czl = bfb(cz - bff(czh));
    uint4 braw;
    if (h == 0) {
        braw.x = cxh | (cxh << 16); braw.y = cxl | (cxl << 16);
        braw.z = cyh | (cyh << 16); braw.w = cyl | (cyl << 16);
    } else {
        braw.x = czh | (czh << 16); braw.y = czl | (czl << 16);
        braw.z = 0x3F803F80u;       braw.w = 0x3F803F80u;   // bf16 1.0 pairs
    }
    return __builtin_bit_cast(bf16x8, braw);
}

// 16->1 untagged min3 tree over raw f32 bits (single positive binade ->
// u32 compare == f32 compare), then fold (m<<9)|tile7 into the chain.
__device__ __forceinline__ void reduce_fold(const f32x16& acc, unsigned tl, unsigned& cm) {
    unsigned u0 = min(min(__float_as_uint(acc[0]),  __float_as_uint(acc[1])),  __float_as_uint(acc[2]));
    unsigned u1 = min(min(__float_as_uint(acc[3]),  __float_as_uint(acc[4])),  __float_as_uint(acc[5]));
    unsigned u2 = min(min(__float_as_uint(acc[6]),  __float_as_uint(acc[7])),  __float_as_uint(acc[8]));
    unsigned u3 = min(min(__float_as_uint(acc[9]),  __float_as_uint(acc[10])), __float_as_uint(acc[11]));
    unsigned u4 = min(min(__float_as_uint(acc[12]), __float_as_uint(acc[13])), __float_as_uint(acc[14]));
    unsigned u5 = min(min(u0, u1), u2);
    unsigned u6 = min(min(u3, u4), __float_as_uint(acc[15]));
    unsigned m  = min(u5, u6);
    cm = min(cm, (m << 9) | tl);
}

// MFMA NN scan, BARRIER-FREE: each wave stages 256-target chunks into its OWN
// 8KB LDS quarter -- only the staging wave reads its writes, so same-wave
// ds_write->ds_read ordering is handled by compiler lgkmcnt waits; there is
// NO __syncthreads in the kernel. Waves free-run (no lockstep stage->barrier
// stall -- the diagnosed ~60%-idle structural cost of R12..R26). 4 query sets
// per wave: each staged tile feeds FOUR MFMAs, amortizing the now-per-wave
// staging. Loads stay coalesced float4 (R25's per-lane 16B scatter was the
// regression there). Key math per chain unchanged: untagged tree,
// (m<<9)|tile7 fold (tile id < 80 fits 7 bits; single positive binade ->
// exact; lower tile wins ties); exact fp32 recheck of the winning tile's 16
// rows per set; lane halves merged via 64-bit shfl_xor; plain store of
// (d2bits<<32)|j into the per-(dir,slice) slot row.
__global__ __launch_bounds__(256, 4) void mfma_nn(
    const float4* __restrict__ adv, int N,
    const float4* __restrict__ ori, int M,
    unsigned long long* __restrict__ slots, int S,   // [2][YSL][S]
    int wchunks)                                      // wave-chunks per slice
{
    const int dir = blockIdx.z;
    const float4* __restrict__ q = dir ? ori : adv;
    const float4* __restrict__ t = dir ? adv : ori;
    const int nq = dir ? M : N;
    const int nt = dir ? N : M;
    unsigned long long* __restrict__ outrow =
        slots + (size_t)(dir * YSL + blockIdx.y) * (size_t)S;

    const int tid = threadIdx.x;
    const int wave = tid >> 6;
    const int lane = tid & 63;
    const int col = lane & 31;
    const int h = lane >> 5;

    const int qi0 = blockIdx.x * QPB + wave * 32 + col;   // set 0
    // sets s at qi0 + s*128
    float4 qp[4]; bool qv[4]; bf16x8 bfrag[4];
    #pragma unroll
    for (int s = 0; s < 4; ++s) {
        int qi = qi0 + s * 128;
        qv[s] = qi < nq;
        qp[s] = qv[s] ? q[qi] : make_float4(0.f, 0.f, 0.f, 0.f);
        bfrag[s] = make_bfrag(qp[s], h);
    }
    const f32x16 zero = {};

    __shared__ uint4 lds_all[4][WTPC * 64];   // 4 waves x 8 KB, private quarters
    uint4* my_lds = lds_all[wave];

    const int slicebase = blockIdx.y * wchunks * WCH;
    unsigned cm0 = 0xFFFFFFFFu, cm1 = 0xFFFFFFFFu;
    unsigned cm2 = 0xFFFFFFFFu, cm3 = 0xFFFFFFFFu;
    int base = slicebase;

    for (int c = 0; c < wchunks; ++c) {
        // wave-private staging: 4 points per lane (coalesced float4 loads)
        {
            bool full = (base + WCH <= nt);
            #pragma unroll
            for (int k = 0; k < 4; ++k) {
                int j = base + k * 64 + lane;
                bool v = full || (j < nt);
                float4 p = v ? t[j] : make_float4(0.f, 0.f, 0.f, 0.f);
                uint4 h0, h1;
                make_frag(p, v, h0, h1);
                int local = k * 64 + lane;       // point index in chunk
                int tl = local >> 5, r = local & 31;
                my_lds[tl * 64 + r]      = h0;   // k-half 0 (lanes 0-31 slots)
                my_lds[tl * 64 + 32 + r] = h1;   // k-half 1
            }
        }
        // same-wave LDS dependency: compiler inserts lgkmcnt waits; no barrier.

        const unsigned tl0 = (unsigned)(c << 3);
        #pragma unroll
        for (int tt = 0; tt < WTPC; ++tt) {
            bf16x8 a = __builtin_bit_cast(bf16x8, my_lds[tt * 64 + lane]);
            f32x16 acc0 = __builtin_amdgcn_mfma_f32_32x32x16_bf16(a, bfrag[0], zero, 0, 0, 0);
            reduce_fold(acc0, tl0 + (unsigned)tt, cm0);
            f32x16 acc1 = __builtin_amdgcn_mfma_f32_32x32x16_bf16(a, bfrag[1], zero, 0, 0, 0);
            reduce_fold(acc1, tl0 + (unsigned)tt, cm1);
            f32x16 acc2 = __builtin_amdgcn_mfma_f32_32x32x16_bf16(a, bfrag[2], zero, 0, 0, 0);
            reduce_fold(acc2, tl0 + (unsigned)tt, cm2);
            f32x16 acc3 = __builtin_amdgcn_mfma_f32_32x32x16_bf16(a, bfrag[3], zero, 0, 0, 0);
            reduce_fold(acc3, tl0 + (unsigned)tt, cm3);
        }
        base += WCH;
    }

    // exact recheck per set: 16 candidate rows of the winning tile (lane-half)
    #pragma unroll
    for (int s = 0; s < 4; ++s) {
        const unsigned cm = (s == 0) ? cm0 : (s == 1) ? cm1 : (s == 2) ? cm2 : cm3;
        const int jb = slicebase + (int)(cm & 0x7Fu) * 32 + 4 * h;
        unsigned long long run = 0xFFFFFFFFFFFFFFFFull;
        #pragma unroll
        for (int e = 0; e < 16; ++e) {
            int r = (e & 3) + ((e >> 2) << 3);  // ascending j within the half
            int j = jb + r;
            if (j < nt) {
                float4 b = t[j];
                float dx = qp[s].x - b.x, dy = qp[s].y - b.y, dz = qp[s].z - b.z;
                float d2 = fmaf(dx, dx, fmaf(dy, dy, dz * dz));
                unsigned long long cand =
                    ((unsigned long long)__float_as_uint(d2) << 32) | (unsigned)j;
                run = cand < run ? cand : run;
            }
        }
        unsigned long long other = __shfl_xor(run, 32);
        run = run < other ? run : other;
        if (h == 0 && qv[s]) outrow[qi0 + s * 128] = run;
    }
}

__device__ inline float block_reduce_sum(float v, float* lds) {
    #pragma unroll
    for (int off = 32; off > 0; off >>= 1) v += __shfl_down(v, off, 64);
    int wave = threadIdx.x >> 6;
    int lane = threadIdx.x & 63;
    __syncthreads();
    if (lane == 0) lds[wave] = v;
    __syncthreads();
    float r = 0.f;
    if (threadIdx.x == 0) {
        #pragma unroll
        for (int w = 0; w < 4; ++w) r += lds[w];
    }
    return r;  // valid on thread 0 only
}

// Stage 1: RB blocks, fixed partition -> deterministic partial sums.
// Per query: u64-min over the YSL slice slots (d2 exact; lower j wins ties ->
// numpy first-occurrence since slice j-ranges ascend).
__global__ __launch_bounds__(256) void partial_finalize(
    const unsigned long long* __restrict__ slots, int S,   // [2][YSL][S]
    int n, int m,
    const float4* __restrict__ adv, const float4* __restrict__ ori,
    float* __restrict__ partials)                           // RB*4 floats
{
    __shared__ float lds[4];
    float s_min0 = 0.f, s_i1 = 0.f, s_min1 = 0.f, s_i2 = 0.f;
    const int stride = RB * 256;
    const int t0 = blockIdx.x * 256 + threadIdx.x;
    const unsigned long long* __restrict__ s0 = slots;
    const unsigned long long* __restrict__ s1 = slots + (size_t)YSL * S;

    for (int i = t0; i < n; i += stride) {
        unsigned long long k = s0[i];
        #pragma unroll
        for (int y = 1; y < YSL; ++y) k = min(k, s0[(size_t)y * S + i]);
        int j = (int)(unsigned int)(k & 0xFFFFFFFFu);
        s_min0 += __uint_as_float((unsigned int)(k >> 32));
        float dw = adv[i].w - ori[j].w;
        s_i1 += dw * dw;
    }
    for (int jj = t0; jj < m; jj += stride) {
        unsigned long long k = s1[jj];
        #pragma unroll
        for (int y = 1; y < YSL; ++y) k = min(k, s1[(size_t)y * S + jj]);
        int i = (int)(unsigned int)(k & 0xFFFFFFFFu);
        s_min1 += __uint_as_float((unsigned int)(k >> 32));
        float dw = ori[jj].w - adv[i].w;
        s_i2 += dw * dw;
    }

    float r0 = block_reduce_sum(s_min0, lds);
    float r1 = block_reduce_sum(s_i1, lds);
    float r2 = block_reduce_sum(s_min1, lds);
    float r3 = block_reduce_sum(s_i2, lds);

    if (threadIdx.x == 0) {
        partials[blockIdx.x * 4 + 0] = r0;
        partials[blockIdx.x * 4 + 1] = r1;
        partials[blockIdx.x * 4 + 2] = r2;
        partials[blockIdx.x * 4 + 3] = r3;
    }
}

__global__ __launch_bounds__(256) void combine(
    const float* __restrict__ partials, int n, int m, float* __restrict__ out)
{
    __shared__ float lds[4];
    float v0 = 0.f, v1 = 0.f, v2 = 0.f, v3 = 0.f;
    if (threadIdx.x < RB) {
        v0 = partials[threadIdx.x * 4 + 0];
        v1 = partials[threadIdx.x * 4 + 1];
        v2 = partials[threadIdx.x * 4 + 2];
        v3 = partials[threadIdx.x * 4 + 3];
    }
    float r0 = block_reduce_sum(v0, lds);
    float r1 = block_reduce_sum(v1, lds);
    float r2 = block_reduce_sum(v2, lds);
    float r3 = block_reduce_sum(v3, lds);
    if (threadIdx.x == 0) {
        float chamfer   = r0 / (float)n + r2 / (float)m;
        float intensity = 0.5f * (r1 / (float)n + r3 / (float)m);
        out[0] = chamfer * 1.0f + intensity * 0.5f;
    }
}

extern "C" void kernel_launch(void* const* d_in, const int* in_sizes, int n_in,
                              void* d_out, int out_size, void* d_ws, size_t ws_size,
                              hipStream_t stream) {
    const float4* adv = (const float4*)d_in[0];
    const float4* ori = (const float4*)d_in[1];
    const int N = in_sizes[0] / 4;
    const int M = in_sizes[1] / 4;
    const int S = max(N, M);

    unsigned long long* slots = (unsigned long long*)d_ws;       // 2*YSL*S entries
    float* partials = (float*)(slots + (size_t)2 * YSL * S);     // RB*4 floats
    float* out = (float*)d_out;

    const int wchunks = (S + YSL * WCH - 1) / (YSL * WCH);       // wave-chunks/slice
    dim3 grid((S + QPB - 1) / QPB, YSL, 2);
    mfma_nn<<<grid, 256, 0, stream>>>(adv, N, ori, M, slots, S, wchunks);

    partial_finalize<<<RB, 256, 0, stream>>>(slots, S, N, M, adv, ori, partials);
    combine<<<1, 256, 0, stream>>>(partials, N, M, out);
}

// Round 28
// 48.723 us; speedup vs baseline: 1.2652x; 1.2652x over previous
//
#include <hip/hip_runtime.h>

#define CH 512          // targets per LDS chunk
#define TPCH 16         // MFMA tiles per chunk (CH/32)
#define QPB 256         // queries per block (4 waves x 2 sets x 32 cols)
#define YSL 6           // target slices: 79*6*2 = 948 blocks <= 1024 resident -> 1 round
#define RB 64           // reduction blocks

typedef __bf16 bf16x8 __attribute__((ext_vector_type(8)));
typedef float f32x16 __attribute__((ext_vector_type(16)));

__device__ __forceinline__ unsigned bfb(float x) {
    __bf16 h = (__bf16)x;
    return (unsigned)__builtin_bit_cast(unsigned short, h);
}
__device__ __forceinline__ float bff(unsigned b) {
    return (float)__builtin_bit_cast(__bf16, (unsigned short)b);
}

// Build the A-fragment (targets) for one local row of the chunk.
// K-slot map (k: A | B):  score = (d2 - |q|^2)/4 + 320, window [304,384) in [256,512)
//  k0..3 : [xh, xl, xh, xl] | [cxh, cxh, cxl, cxl]   (full (xh+xl)(cxh+cxl))
//  k4..7 : [yh, yl, yh, yl] | [cyh, cyh, cyl, cyl]
//  k8..11: [zh, zl, zh, zl] | [czh, czh, czl, czl]
//  k12..15:[uh, ul, ull,320]| [1, 1, 1, 1]           (u = |t|^2/4, 3-term split)
// Sentinel rows: coords 0, u=130 -> score 450 (in-window, never beats real <384).
// NOTE (R20): this conversion VALU is free -- it hides under staging load latency.
__device__ __forceinline__ void stage_one(uint4* a_lds, int local, float4 p, bool valid) {
    float x, y, z, u;
    if (valid) {
        x = p.x; y = p.y; z = p.z;
        u = 0.25f * fmaf(p.x, p.x, fmaf(p.y, p.y, p.z * p.z));
    } else {
        x = 0.f; y = 0.f; z = 0.f; u = 130.f;
    }
    unsigned xh = bfb(x); unsigned xl = bfb(x - bff(xh));
    unsigned yh = bfb(y); unsigned yl = bfb(y - bff(yh));
    unsigned zh = bfb(z); unsigned zl = bfb(z - bff(zh));
    unsigned uh = bfb(u); float u1 = u - bff(uh);
    unsigned ul = bfb(u1); unsigned ull = bfb(u1 - bff(ul));
    uint4 h0, h1;
    h0.x = xh | (xl << 16); h0.y = h0.x;
    h0.z = yh | (yl << 16); h0.w = h0.z;
    h1.x = zh | (zl << 16); h1.y = h1.x;
    h1.z = uh | (ul << 16);
    h1.w = ull | (0x43A0u << 16);      // [ull, bf16(320)]
    int t = local >> 5, r = local & 31;
    a_lds[t * 64 + r]      = h0;       // k-half 0 (lanes 0-31)
    a_lds[t * 64 + 32 + r] = h1;       // k-half 1 (lanes 32-63)
}

// build B fragment for one query point (c = -q/2 split hi/lo)
__device__ __forceinline__ bf16x8 make_bfrag(float4 qp, int h) {
    float cx = -0.5f * qp.x, cy = -0.5f * qp.y, cz = -0.5f * qp.z;
    unsigned cxh = bfb(cx); unsigned cxl = bfb(cx - bff(cxh));
    unsigned cyh = bfb(cy); unsigned cyl = bfb(cy - bff(cyh));
    unsigned czh = bfb(cz); unsigned czl = bfb(cz - bff(czh));
    uint4 braw;
    if (h == 0) {
        braw.x = cxh | (cxh << 16); braw.y = cxl | (cxl << 16);
        braw.z = cyh | (cyh << 16); braw.w = cyl | (cyl << 16);
    } else {
        braw.x = czh | (czh << 16); braw.y = czl | (czl << 16);
        braw.z = 0x3F803F80u;       braw.w = 0x3F803F80u;   // bf16 1.0 pairs
    }
    return __builtin_bit_cast(bf16x8, braw);
}

// 16->1 untagged min3 tree over raw f32 bits (single positive binade ->
// u32 compare == f32 compare), then fold (m<<9)|tile7 into the chain.
__device__ __forceinline__ void reduce_fold(const f32x16& acc, unsigned tl, unsigned& cm) {
    unsigned u0 = min(min(__float_as_uint(acc[0]),  __float_as_uint(acc[1])),  __float_as_uint(acc[2]));
    unsigned u1 = min(min(__float_as_uint(acc[3]),  __float_as_uint(acc[4])),  __float_as_uint(acc[5]));
    unsigned u2 = min(min(__float_as_uint(acc[6]),  __float_as_uint(acc[7])),  __float_as_uint(acc[8]));
    unsigned u3 = min(min(__float_as_uint(acc[9]),  __float_as_uint(acc[10])), __float_as_uint(acc[11]));
    unsigned u4 = min(min(__float_as_uint(acc[12]), __float_as_uint(acc[13])), __float_as_uint(acc[14]));
    unsigned u5 = min(min(u0, u1), u2);
    unsigned u6 = min(min(u3, u4), __float_as_uint(acc[15]));
    unsigned m  = min(u5, u6);
    cm = min(cm, (m << 9) | tl);
}

// MFMA NN scan, 2 query sets per wave (R23 structure), YSL=6 so the whole
// grid (948 blocks) is co-resident in ONE dispatch round (blocks/CU pins at
// ~4 empirically -> capacity 1024; R23's 1264 blocks ran 1.23 rounds with a
// mostly-idle tail = the measured 34% time-avg occupancy). 7 chunks/slice,
// 112 tiles < 128 fits the 7-bit tile field; padded tiles use sentinels.
// Key math per chain: untagged tree, (m<<9)|tile7 fold (single positive
// binade -> exact), lower tile wins ties; exact fp32 recheck of the winning
// tile's 16 rows per set; lane halves merged via 64-bit shfl_xor; plain
// store of (d2bits<<32)|j into the per-(dir,slice) slot row.
__global__ __launch_bounds__(256, 8) void mfma_nn(
    const float4* __restrict__ adv, int N,
    const float4* __restrict__ ori, int M,
    unsigned long long* __restrict__ slots, int S,   // [2][YSL][S]
    int chunks)
{
    const int dir = blockIdx.z;
    const float4* __restrict__ q = dir ? ori : adv;
    const float4* __restrict__ t = dir ? adv : ori;
    const int nq = dir ? M : N;
    const int nt = dir ? N : M;
    unsigned long long* __restrict__ outrow =
        slots + (size_t)(dir * YSL + blockIdx.y) * (size_t)S;

    const int tid = threadIdx.x;
    const int wave = tid >> 6;
    const int lane = tid & 63;
    const int col = lane & 31;
    const int h = lane >> 5;

    const int qiA = blockIdx.x * QPB + wave * 32 + col;        // set A: cols 0..127
    const int qiB = qiA + 128;                                  // set B: cols 128..255
    const bool qvA = qiA < nq;
    const bool qvB = qiB < nq;
    float4 qpA = qvA ? q[qiA] : make_float4(0.f, 0.f, 0.f, 0.f);
    float4 qpB = qvB ? q[qiB] : make_float4(0.f, 0.f, 0.f, 0.f);

    const bf16x8 bfragA = make_bfrag(qpA, h);
    const bf16x8 bfragB = make_bfrag(qpB, h);

    __shared__ uint4 a_lds[TPCH * 64];
    const f32x16 zero = {};

    const int slicebase = blockIdx.y * chunks * CH;
    unsigned cmA = 0xFFFFFFFFu;     // (mant23 << 9) | tile7, set A
    unsigned cmB = 0xFFFFFFFFu;     //                         set B
    int base = slicebase;

    for (int c = 0; c < chunks; ++c) {
        if (c) __syncthreads();                 // prior tile reads done
        {
            int j0 = base + tid, j1 = j0 + 256;
            if (base + CH <= nt) {              // block-uniform fast path
                stage_one(a_lds, tid,       t[j0], true);
                stage_one(a_lds, tid + 256, t[j1], true);
            } else {
                bool v0 = j0 < nt, v1 = j1 < nt;
                float4 p0 = v0 ? t[j0] : make_float4(0.f, 0.f, 0.f, 0.f);
                float4 p1 = v1 ? t[j1] : make_float4(0.f, 0.f, 0.f, 0.f);
                stage_one(a_lds, tid,       p0, v0);
                stage_one(a_lds, tid + 256, p1, v1);
            }
        }
        __syncthreads();

        const unsigned tl0 = (unsigned)(c << 4);
        #pragma unroll
        for (int tt = 0; tt < TPCH; ++tt) {
            bf16x8 a = __builtin_bit_cast(bf16x8, a_lds[tt * 64 + lane]);
            f32x16 acc0 = __builtin_amdgcn_mfma_f32_32x32x16_bf16(a, bfragA, zero, 0, 0, 0);
            reduce_fold(acc0, tl0 + (unsigned)tt, cmA);
            f32x16 acc1 = __builtin_amdgcn_mfma_f32_32x32x16_bf16(a, bfragB, zero, 0, 0, 0);
            reduce_fold(acc1, tl0 + (unsigned)tt, cmB);
        }
        base += CH;
    }

    // exact recheck per set: 16 candidate rows of the winning tile (lane-half)
    #pragma unroll
    for (int s = 0; s < 2; ++s) {
        const unsigned cm = s ? cmB : cmA;
        const float4 qp  = s ? qpB : qpA;
        const int    qi  = s ? qiB : qiA;
        const bool   qv  = s ? qvB : qvA;
        const int jb = slicebase + (int)(cm & 0x7Fu) * 32 + 4 * h;
        unsigned long long run = 0xFFFFFFFFFFFFFFFFull;
        #pragma unroll
        for (int e = 0; e < 16; ++e) {
            int r = (e & 3) + ((e >> 2) << 3);  // ascending j within the half
            int j = jb + r;
            if (j < nt) {
                float4 b = t[j];
                float dx = qp.x - b.x, dy = qp.y - b.y, dz = qp.z - b.z;
                float d2 = fmaf(dx, dx, fmaf(dy, dy, dz * dz));
                unsigned long long cand =
                    ((unsigned long long)__float_as_uint(d2) << 32) | (unsigned)j;
                run = cand < run ? cand : run;
            }
        }
        unsigned long long other = __shfl_xor(run, 32);
        run = run < other ? run : other;
        if (h == 0 && qv) outrow[qi] = run;
    }
}

__device__ inline float block_reduce_sum(float v, float* lds) {
    #pragma unroll
    for (int off = 32; off > 0; off >>= 1) v += __shfl_down(v, off, 64);
    int wave = threadIdx.x >> 6;
    int lane = threadIdx.x & 63;
    __syncthreads();
    if (lane == 0) lds[wave] = v;
    __syncthreads();
    float r = 0.f;
    if (threadIdx.x == 0) {
        #pragma unroll
        for (int w = 0; w < 4; ++w) r += lds[w];
    }
    return r;  // valid on thread 0 only
}

// Stage 1: RB blocks, fixed partition -> deterministic partial sums.
// Per query: u64-min over the YSL slice slots (d2 exact; lower j wins ties ->
// numpy first-occurrence since slice j-ranges ascend).
__global__ __launch_bounds__(256) void partial_finalize(
    const unsigned long long* __restrict__ slots, int S,   // [2][YSL][S]
    int n, int m,
    const float4* __restrict__ adv, const float4* __restrict__ ori,
    float* __restrict__ partials)                           // RB*4 floats
{
    __shared__ float lds[4];
    float s_min0 = 0.f, s_i1 = 0.f, s_min1 = 0.f, s_i2 = 0.f;
    const int stride = RB * 256;
    const int t0 = blockIdx.x * 256 + threadIdx.x;
    const unsigned long long* __restrict__ s0 = slots;
    const unsigned long long* __restrict__ s1 = slots + (size_t)YSL * S;

    for (int i = t0; i < n; i += stride) {
        unsigned long long k = s0[i];
        #pragma unroll
        for (int y = 1; y < YSL; ++y) k = min(k, s0[(size_t)y * S + i]);
        int j = (int)(unsigned int)(k & 0xFFFFFFFFu);
        s_min0 += __uint_as_float((unsigned int)(k >> 32));
        float dw = adv[i].w - ori[j].w;
        s_i1 += dw * dw;
    }
    for (int jj = t0; jj < m; jj += stride) {
        unsigned long long k = s1[jj];
        #pragma unroll
        for (int y = 1; y < YSL; ++y) k = min(k, s1[(size_t)y * S + jj]);
        int i = (int)(unsigned int)(k & 0xFFFFFFFFu);
        s_min1 += __uint_as_float((unsigned int)(k >> 32));
        float dw = ori[jj].w - adv[i].w;
        s_i2 += dw * dw;
    }

    float r0 = block_reduce_sum(s_min0, lds);
    float r1 = block_reduce_sum(s_i1, lds);
    float r2 = block_reduce_sum(s_min1, lds);
    float r3 = block_reduce_sum(s_i2, lds);

    if (threadIdx.x == 0) {
        partials[blockIdx.x * 4 + 0] = r0;
        partials[blockIdx.x * 4 + 1] = r1;
        partials[blockIdx.x * 4 + 2] = r2;
        partials[blockIdx.x * 4 + 3] = r3;
    }
}

__global__ __launch_bounds__(256) void combine(
    const float* __restrict__ partials, int n, int m, float* __restrict__ out)
{
    __shared__ float lds[4];
    float v0 = 0.f, v1 = 0.f, v2 = 0.f, v3 = 0.f;
    if (threadIdx.x < RB) {
        v0 = partials[threadIdx.x * 4 + 0];
        v1 = partials[threadIdx.x * 4 + 1];
        v2 = partials[threadIdx.x * 4 + 2];
        v3 = partials[threadIdx.x * 4 + 3];
    }
    float r0 = block_reduce_sum(v0, lds);
    float r1 = block_reduce_sum(v1, lds);
    float r2 = block_reduce_sum(v2, lds);
    float r3 = block_reduce_sum(v3, lds);
    if (threadIdx.x == 0) {
        float chamfer   = r0 / (float)n + r2 / (float)m;
        float intensity = 0.5f * (r1 / (float)n + r3 / (float)m);
        out[0] = chamfer * 1.0f + intensity * 0.5f;
    }
}

extern "C" void kernel_launch(void* const* d_in, const int* in_sizes, int n_in,
                              void* d_out, int out_size, void* d_ws, size_t ws_size,
                              hipStream_t stream) {
    const float4* adv = (const float4*)d_in[0];
    const float4* ori = (const float4*)d_in[1];
    const int N = in_sizes[0] / 4;
    const int M = in_sizes[1] / 4;
    const int S = max(N, M);

    unsigned long long* slots = (unsigned long long*)d_ws;       // 2*YSL*S entries
    float* partials = (float*)(slots + (size_t)2 * YSL * S);     // RB*4 floats
    float* out = (float*)d_out;

    const int chunks = (S + YSL * CH - 1) / (YSL * CH);          // chunks per slice
    dim3 grid((S + QPB - 1) / QPB, YSL, 2);
    mfma_nn<<<grid, 256, 0, stream>>>(adv, N, ori, M, slots, S, chunks);

    partial_finalize<<<RB, 256, 0, stream>>>(slots, S, N, M, adv, ori, partials);
    combine<<<1, 256, 0, stream>>>(partials, N, M, out);
}

// Round 29
// 45.992 us; speedup vs baseline: 1.3404x; 1.0594x over previous
//
#include <hip/hip_runtime.h>

#define CH 512          // targets per LDS chunk
#define TPCH 16         // MFMA tiles per chunk (CH/32)
#define QPB 256         // queries per block (4 waves x 2 sets x 32 cols)
#define YSL 8           // target slices (grid.y)
#define RB 128          // reduction blocks

typedef __bf16 bf16x8 __attribute__((ext_vector_type(8)));
typedef float f32x16 __attribute__((ext_vector_type(16)));

__device__ __forceinline__ unsigned bfb(float x) {
    __bf16 h = (__bf16)x;
    return (unsigned)__builtin_bit_cast(unsigned short, h);
}
__device__ __forceinline__ float bff(unsigned b) {
    return (float)__builtin_bit_cast(__bf16, (unsigned short)b);
}

// Build the A-fragment (targets) for one local row of the chunk.
// K-slot map (k: A | B):  score = (d2 - |q|^2)/4 + 320, window [304,384) in [256,512)
//  k0..3 : [xh, xl, xh, xl] | [cxh, cxh, cxl, cxl]   (full (xh+xl)(cxh+cxl))
//  k4..7 : [yh, yl, yh, yl] | [cyh, cyh, cyl, cyl]
//  k8..11: [zh, zl, zh, zl] | [czh, czh, czl, czl]
//  k12..15:[uh, ul, ull,320]| [1, 1, 1, 1]           (u = |t|^2/4, 3-term split)
// Sentinel rows: coords 0, u=130 -> score 450 (in-window, never beats real <384).
// NOTE (R20): this conversion VALU is free -- it hides under staging load latency.
__device__ __forceinline__ void stage_one(uint4* a_lds, int local, float4 p, bool valid) {
    float x, y, z, u;
    if (valid) {
        x = p.x; y = p.y; z = p.z;
        u = 0.25f * fmaf(p.x, p.x, fmaf(p.y, p.y, p.z * p.z));
    } else {
        x = 0.f; y = 0.f; z = 0.f; u = 130.f;
    }
    unsigned xh = bfb(x); unsigned xl = bfb(x - bff(xh));
    unsigned yh = bfb(y); unsigned yl = bfb(y - bff(yh));
    unsigned zh = bfb(z); unsigned zl = bfb(z - bff(zh));
    unsigned uh = bfb(u); float u1 = u - bff(uh);
    unsigned ul = bfb(u1); unsigned ull = bfb(u1 - bff(ul));
    uint4 h0, h1;
    h0.x = xh | (xl << 16); h0.y = h0.x;
    h0.z = yh | (yl << 16); h0.w = h0.z;
    h1.x = zh | (zl << 16); h1.y = h1.x;
    h1.z = uh | (ul << 16);
    h1.w = ull | (0x43A0u << 16);      // [ull, bf16(320)]
    int t = local >> 5, r = local & 31;
    a_lds[t * 64 + r]      = h0;       // k-half 0 (lanes 0-31)
    a_lds[t * 64 + 32 + r] = h1;       // k-half 1 (lanes 32-63)
}

// build B fragment for one query point (c = -q/2 split hi/lo)
__device__ __forceinline__ bf16x8 make_bfrag(float4 qp, int h) {
    float cx = -0.5f * qp.x, cy = -0.5f * qp.y, cz = -0.5f * qp.z;
    unsigned cxh = bfb(cx); unsigned cxl = bfb(cx - bff(cxh));
    unsigned cyh = bfb(cy); unsigned cyl = bfb(cy - bff(cyh));
    unsigned czh = bfb(cz); unsigned czl = bfb(cz - bff(czh));
    uint4 braw;
    if (h == 0) {
        braw.x = cxh | (cxh << 16); braw.y = cxl | (cxl << 16);
        braw.z = cyh | (cyh << 16); braw.w = cyl | (cyl << 16);
    } else {
        braw.x = czh | (czh << 16); braw.y = czl | (czl << 16);
        braw.z = 0x3F803F80u;       braw.w = 0x3F803F80u;   // bf16 1.0 pairs
    }
    return __builtin_bit_cast(bf16x8, braw);
}

// 16->1 untagged min3 tree over raw f32 bits (single positive binade ->
// u32 compare == f32 compare), then fold (m<<9)|tile7 into the chain.
__device__ __forceinline__ void reduce_fold(const f32x16& acc, unsigned tl, unsigned& cm) {
    unsigned u0 = min(min(__float_as_uint(acc[0]),  __float_as_uint(acc[1])),  __float_as_uint(acc[2]));
    unsigned u1 = min(min(__float_as_uint(acc[3]),  __float_as_uint(acc[4])),  __float_as_uint(acc[5]));
    unsigned u2 = min(min(__float_as_uint(acc[6]),  __float_as_uint(acc[7])),  __float_as_uint(acc[8]));
    unsigned u3 = min(min(__float_as_uint(acc[9]),  __float_as_uint(acc[10])), __float_as_uint(acc[11]));
    unsigned u4 = min(min(__float_as_uint(acc[12]), __float_as_uint(acc[13])), __float_as_uint(acc[14]));
    unsigned u5 = min(min(u0, u1), u2);
    unsigned u6 = min(min(u3, u4), __float_as_uint(acc[15]));
    unsigned m  = min(u5, u6);
    cm = min(cm, (m << 9) | tl);
}

// MFMA NN scan, 2 query sets per wave (best-measured structure, R22/R23):
// each a_lds tile read feeds TWO MFMAs (B-fragments A and B = 2x32 query
// cols), halving device-total staging and LDS-read work per pair.
// Key math per chain: untagged tree, (m<<9)|tile7 fold (single positive
// binade -> exact), lower tile wins ties; exact fp32 recheck of the winning
// tile's 16 rows per set; lane halves merged via 64-bit shfl_xor; plain
// store of (d2bits<<32)|j into the per-(dir,slice) slot row.
__global__ __launch_bounds__(256, 4) void mfma_nn(
    const float4* __restrict__ adv, int N,
    const float4* __restrict__ ori, int M,
    unsigned long long* __restrict__ slots, int S,   // [2][YSL][S]
    int chunks)
{
    const int dir = blockIdx.z;
    const float4* __restrict__ q = dir ? ori : adv;
    const float4* __restrict__ t = dir ? adv : ori;
    const int nq = dir ? M : N;
    const int nt = dir ? N : M;
    unsigned long long* __restrict__ outrow =
        slots + (size_t)(dir * YSL + blockIdx.y) * (size_t)S;

    const int tid = threadIdx.x;
    const int wave = tid >> 6;
    const int lane = tid & 63;
    const int col = lane & 31;
    const int h = lane >> 5;

    const int qiA = blockIdx.x * QPB + wave * 32 + col;        // set A: cols 0..127
    const int qiB = qiA + 128;                                  // set B: cols 128..255
    const bool qvA = qiA < nq;
    const bool qvB = qiB < nq;
    float4 qpA = qvA ? q[qiA] : make_float4(0.f, 0.f, 0.f, 0.f);
    float4 qpB = qvB ? q[qiB] : make_float4(0.f, 0.f, 0.f, 0.f);

    const bf16x8 bfragA = make_bfrag(qpA, h);
    const bf16x8 bfragB = make_bfrag(qpB, h);

    __shared__ uint4 a_lds[TPCH * 64];
    const f32x16 zero = {};

    const int slicebase = blockIdx.y * chunks * CH;
    unsigned cmA = 0xFFFFFFFFu;     // (mant23 << 9) | tile7, set A
    unsigned cmB = 0xFFFFFFFFu;     //                         set B
    int base = slicebase;

    for (int c = 0; c < chunks; ++c) {
        if (c) __syncthreads();                 // prior tile reads done
        {
            int j0 = base + tid, j1 = j0 + 256;
            if (base + CH <= nt) {              // block-uniform fast path
                stage_one(a_lds, tid,       t[j0], true);
                stage_one(a_lds, tid + 256, t[j1], true);
            } else {
                bool v0 = j0 < nt, v1 = j1 < nt;
                float4 p0 = v0 ? t[j0] : make_float4(0.f, 0.f, 0.f, 0.f);
                float4 p1 = v1 ? t[j1] : make_float4(0.f, 0.f, 0.f, 0.f);
                stage_one(a_lds, tid,       p0, v0);
                stage_one(a_lds, tid + 256, p1, v1);
            }
        }
        __syncthreads();

        const unsigned tl0 = (unsigned)(c << 4);
        #pragma unroll
        for (int tt = 0; tt < TPCH; ++tt) {
            bf16x8 a = __builtin_bit_cast(bf16x8, a_lds[tt * 64 + lane]);
            f32x16 acc0 = __builtin_amdgcn_mfma_f32_32x32x16_bf16(a, bfragA, zero, 0, 0, 0);
            reduce_fold(acc0, tl0 + (unsigned)tt, cmA);
            f32x16 acc1 = __builtin_amdgcn_mfma_f32_32x32x16_bf16(a, bfragB, zero, 0, 0, 0);
            reduce_fold(acc1, tl0 + (unsigned)tt, cmB);
        }
        base += CH;
    }

    // exact recheck per set: 16 candidate rows of the winning tile (lane-half)
    #pragma unroll
    for (int s = 0; s < 2; ++s) {
        const unsigned cm = s ? cmB : cmA;
        const float4 qp  = s ? qpB : qpA;
        const int    qi  = s ? qiB : qiA;
        const bool   qv  = s ? qvB : qvA;
        const int jb = slicebase + (int)(cm & 0x7Fu) * 32 + 4 * h;
        unsigned long long run = 0xFFFFFFFFFFFFFFFFull;
        #pragma unroll
        for (int e = 0; e < 16; ++e) {
            int r = (e & 3) + ((e >> 2) << 3);  // ascending j within the half
            int j = jb + r;
            if (j < nt) {
                float4 b = t[j];
                float dx = qp.x - b.x, dy = qp.y - b.y, dz = qp.z - b.z;
                float d2 = fmaf(dx, dx, fmaf(dy, dy, dz * dz));
                unsigned long long cand =
                    ((unsigned long long)__float_as_uint(d2) << 32) | (unsigned)j;
                run = cand < run ? cand : run;
            }
        }
        unsigned long long other = __shfl_xor(run, 32);
        run = run < other ? run : other;
        if (h == 0 && qv) outrow[qi] = run;
    }
}

__device__ inline float block_reduce_sum(float v, float* lds) {
    #pragma unroll
    for (int off = 32; off > 0; off >>= 1) v += __shfl_down(v, off, 64);
    int wave = threadIdx.x >> 6;
    int lane = threadIdx.x & 63;
    __syncthreads();
    if (lane == 0) lds[wave] = v;
    __syncthreads();
    float r = 0.f;
    if (threadIdx.x == 0) {
        #pragma unroll
        for (int w = 0; w < 4; ++w) r += lds[w];
    }
    return r;  // valid on thread 0 only
}

// Stage 1: RB blocks, fixed partition -> deterministic partial sums.
// Per query: u64-min over the YSL slice slots (d2 exact; lower j wins ties ->
// numpy first-occurrence since slice j-ranges ascend).
__global__ __launch_bounds__(256) void partial_finalize(
    const unsigned long long* __restrict__ slots, int S,   // [2][YSL][S]
    int n, int m,
    const float4* __restrict__ adv, const float4* __restrict__ ori,
    float* __restrict__ partials)                           // RB*4 floats
{
    __shared__ float lds[4];
    float s_min0 = 0.f, s_i1 = 0.f, s_min1 = 0.f, s_i2 = 0.f;
    const int stride = RB * 256;
    const int t0 = blockIdx.x * 256 + threadIdx.x;
    const unsigned long long* __restrict__ s0 = slots;
    const unsigned long long* __restrict__ s1 = slots + (size_t)YSL * S;

    for (int i = t0; i < n; i += stride) {
        unsigned long long k = s0[i];
        #pragma unroll
        for (int y = 1; y < YSL; ++y) k = min(k, s0[(size_t)y * S + i]);
        int j = (int)(unsigned int)(k & 0xFFFFFFFFu);
        s_min0 += __uint_as_float((unsigned int)(k >> 32));
        float dw = adv[i].w - ori[j].w;
        s_i1 += dw * dw;
    }
    for (int jj = t0; jj < m; jj += stride) {
        unsigned long long k = s1[jj];
        #pragma unroll
        for (int y = 1; y < YSL; ++y) k = min(k, s1[(size_t)y * S + jj]);
        int i = (int)(unsigned int)(k & 0xFFFFFFFFu);
        s_min1 += __uint_as_float((unsigned int)(k >> 32));
        float dw = ori[jj].w - adv[i].w;
        s_i2 += dw * dw;
    }

    float r0 = block_reduce_sum(s_min0, lds);
    float r1 = block_reduce_sum(s_i1, lds);
    float r2 = block_reduce_sum(s_min1, lds);
    float r3 = block_reduce_sum(s_i2, lds);

    if (threadIdx.x == 0) {
        partials[blockIdx.x * 4 + 0] = r0;
        partials[blockIdx.x * 4 + 1] = r1;
        partials[blockIdx.x * 4 + 2] = r2;
        partials[blockIdx.x * 4 + 3] = r3;
    }
}

__global__ __launch_bounds__(256) void combine(
    const float* __restrict__ partials, int n, int m, float* __restrict__ out)
{
    __shared__ float lds[4];
    float v0 = 0.f, v1 = 0.f, v2 = 0.f, v3 = 0.f;
    if (threadIdx.x < RB) {
        v0 = partials[threadIdx.x * 4 + 0];
        v1 = partials[threadIdx.x * 4 + 1];
        v2 = partials[threadIdx.x * 4 + 2];
        v3 = partials[threadIdx.x * 4 + 3];
    }
    float r0 = block_reduce_sum(v0, lds);
    float r1 = block_reduce_sum(v1, lds);
    float r2 = block_reduce_sum(v2, lds);
    float r3 = block_reduce_sum(v3, lds);
    if (threadIdx.x == 0) {
        float chamfer   = r0 / (float)n + r2 / (float)m;
        float intensity = 0.5f * (r1 / (float)n + r3 / (float)m);
        out[0] = chamfer * 1.0f + intensity * 0.5f;
    }
}

extern "C" void kernel_launch(void* const* d_in, const int* in_sizes, int n_in,
                              void* d_out, int out_size, void* d_ws, size_t ws_size,
                              hipStream_t stream) {
    const float4* adv = (const float4*)d_in[0];
    const float4* ori = (const float4*)d_in[1];
    const int N = in_sizes[0] / 4;
    const int M = in_sizes[1] / 4;
    const int S = max(N, M);

    unsigned long long* slots = (unsigned long long*)d_ws;       // 2*YSL*S entries
    float* partials = (float*)(slots + (size_t)2 * YSL * S);     // RB*4 floats
    float* out = (float*)d_out;

    const int chunks = (S + YSL * CH - 1) / (YSL * CH);          // chunks per slice
    dim3 grid((S + QPB - 1) / QPB, YSL, 2);
    mfma_nn<<<grid, 256, 0, stream>>>(adv, N, ori, M, slots, S, chunks);

    partial_finalize<<<RB, 256, 0, stream>>>(slots, S, N, M, adv, ori, partials);
    combine<<<1, 256, 0, stream>>>(partials, N, M, out);
}